// Round 16
// baseline (385.660 us; speedup 1.0000x reference)
//
#include <hip/hip_runtime.h>
#include <hip/hip_bf16.h>
#include <hip/hip_cooperative_groups.h>
#include <float.h>

namespace cg = cooperative_groups;

#define B_ 2
#define N_ 2048
#define DIM_ 1024
#define HEADS_ 8
#define DH_ 64
#define NUM_MEM_ 4
#define ROWS_ (B_ * N_)          // 4096
#define QCOLS_ (HEADS_ * DH_)    // 512
#define JTOT_ (N_ + NUM_MEM_)    // 2052
#define JPAD_ 2176               // 17 * 128
#define CHUNKS_PER_BH_ 77        // sum over qt of ceil((qt+2)/9)
#define SMEM_BYTES 27648

typedef __attribute__((ext_vector_type(8))) short short8v;
typedef __attribute__((ext_vector_type(4))) float f32x4;

static __device__ __forceinline__ ushort f2b(float f) {
    __hip_bfloat16 hb = __float2bfloat16(f);
    return *(ushort*)&hb;
}
static __device__ __forceinline__ uint pk2(float a, float b) {
    return ((uint)f2b(b) << 16) | (uint)f2b(a);
}
static __device__ __forceinline__ float b2f_lo(uint u) {
    union { uint x; float f; } c; c.x = u << 16; return c.f;
}
static __device__ __forceinline__ float b2f_hi(uint u) {
    union { uint x; float f; } c; c.x = u & 0xffff0000u; return c.f;
}

// ---------------- phase 1a: LayerNorm + dual bf16 cast ----------------
static __device__ __forceinline__ void ln_body(char* smem, int row,
                                               const float* __restrict__ x,
                                               const float* __restrict__ gamma,
                                               ushort* __restrict__ xb,
                                               ushort* __restrict__ xnb) {
    float* ws1 = (float*)smem;
    float* ws2 = ws1 + 4;
    const float4 v = ((const float4*)(x + (size_t)row * DIM_))[threadIdx.x];
    float s  = v.x + v.y + v.z + v.w;
    float s2 = v.x * v.x + v.y * v.y + v.z * v.z + v.w * v.w;
    #pragma unroll
    for (int off = 32; off > 0; off >>= 1) {
        s  += __shfl_down(s, off);
        s2 += __shfl_down(s2, off);
    }
    int lane = threadIdx.x & 63, wid = threadIdx.x >> 6;
    if (lane == 0) { ws1[wid] = s; ws2[wid] = s2; }
    __syncthreads();
    float tot  = ws1[0] + ws1[1] + ws1[2] + ws1[3];
    float tot2 = ws2[0] + ws2[1] + ws2[2] + ws2[3];
    float mu  = tot * (1.0f / DIM_);
    float var = tot2 * (1.0f / DIM_) - mu * mu;
    float rs  = rsqrtf(var + 1e-5f);
    const float4 g = ((const float4*)gamma)[threadIdx.x];
    float vv[4] = {v.x, v.y, v.z, v.w};
    float gg[4] = {g.x, g.y, g.z, g.w};
    ushort xo[4], xno[4];
    #pragma unroll
    for (int j = 0; j < 4; ++j) {
        xo[j]  = f2b(vv[j]);
        xno[j] = f2b((vv[j] - mu) * rs * gg[j]);
    }
    *(int2*)(xb  + (size_t)row * DIM_ + threadIdx.x * 4) = *(int2*)xo;
    *(int2*)(xnb + (size_t)row * DIM_ + threadIdx.x * 4) = *(int2*)xno;
    __syncthreads();   // protect ws reuse by next stride iteration
}

// ---------------- phase 1b: weight transposes + KV seed + amask ----------------
static __device__ __forceinline__ void wtrans_body(const float* __restrict__ W,
                                                   ushort* __restrict__ Wt,
                                                   int K, int N, int t) {
    int n = t % N;
    int k0 = (t / N) * 8;
    ushort u[8];
    #pragma unroll
    for (int j = 0; j < 8; ++j) u[j] = f2b(W[(size_t)(k0 + j) * N + n]);
    *(int4*)(Wt + (size_t)n * K + k0) = *(int4*)u;
}

static __device__ __forceinline__ void prep_body(int bid,
                                                 const float* __restrict__ Wq,
                                                 const float* __restrict__ Wkv,
                                                 const float* __restrict__ Wout,
                                                 const float* __restrict__ mem_kv,
                                                 const int* __restrict__ mask,
                                                 ushort* __restrict__ Wqt,
                                                 ushort* __restrict__ Wkvt,
                                                 ushort* __restrict__ Woutt,
                                                 ushort* __restrict__ Kb,
                                                 ushort* __restrict__ Vt,
                                                 ushort* __restrict__ amask) {
    int tid = threadIdx.x;
    if (bid < 256) {
        wtrans_body(Wq, Wqt, DIM_, QCOLS_, bid * 256 + tid);
    } else if (bid < 320) {
        wtrans_body(Wkv, Wkvt, DIM_, 2 * DH_, (bid - 256) * 256 + tid);
    } else if (bid < 576) {
        wtrans_body(Wout, Woutt, QCOLS_, DIM_, (bid - 320) * 256 + tid);
    } else if (bid < 640) {
        int t = (bid - 576) * 256 + tid;
        int d  = t & 63;
        int ji = (t >> 6) & 127;
        int b  = t >> 13;
        int j  = (ji < NUM_MEM_) ? ji : (2048 + ji);
        float kv_ = 0.f, vv = 0.f;
        if (ji < NUM_MEM_) {
            kv_ = mem_kv[ji * DH_ + d];
            vv  = mem_kv[NUM_MEM_ * DH_ + ji * DH_ + d];
        }
        Kb[((size_t)(b * JPAD_) + j) * DH_ + d] = f2b(kv_);
        Vt[((size_t)(b * DH_) + d) * JPAD_ + j] = f2b(vv);
    } else {
        int t = (bid - 640) * 256 + tid;
        if (t < B_ * JPAD_) {
            int b = t / JPAD_;
            int j = t % JPAD_;
            float v;
            if (j < NUM_MEM_) v = 0.f;
            else if (j < JTOT_) v = mask[b * N_ + (j - NUM_MEM_)] ? 0.f : -1e30f;
            else v = -1e30f;
            amask[(size_t)b * JPAD_ + j] = f2b(v);
        }
    }
}

// ---------------- phase 2: bf16 MFMA GEMM body, BM=64, BK=32 ----------------
// MODE 0: qb (bf16, *0.125)   MODE 1: Kb / Vt scatter
template<int MODE>
static __device__ __forceinline__ void gemm64_body(char* smem,
                                                   const ushort* __restrict__ A,
                                                   const ushort* __restrict__ Bt,
                                                   void* __restrict__ C,
                                                   void* __restrict__ C2,
                                                   int K, int bx, int by) {
    ushort (*As)[40] = (ushort(*)[40])smem;
    ushort (*Bs)[40] = (ushort(*)[40])(smem + 64 * 40 * 2);
    int tid = threadIdx.x;
    int w = tid >> 6, l = tid & 63, lg = l >> 4, ll = l & 15;
    int r0 = by * 64, c0 = bx * 64;

    int arow = tid >> 2;
    int achk = (tid & 3) * 8;
    const ushort* Ap = A + (size_t)(r0 + arow) * K + achk;
    const ushort* Bp = Bt + (size_t)(c0 + arow) * K + achk;

    int4 a0 = *(const int4*)Ap;
    int4 b0 = *(const int4*)Bp;

    f32x4 acc[4] = {};

    int nk = K / 32;
    for (int ks = 0; ks < nk; ++ks) {
        __syncthreads();
        *(int4*)&As[arow][achk] = a0;
        *(int4*)&Bs[arow][achk] = b0;
        __syncthreads();
        int kn = (ks + 1 < nk) ? (ks + 1) * 32 : 0;   // wrap: dummy re-read
        a0 = *(const int4*)(Ap + kn);
        b0 = *(const int4*)(Bp + kn);
        short8v af, bf[4];
        af = *(const short8v*)&As[w * 16 + ll][lg * 8];
        #pragma unroll
        for (int ct = 0; ct < 4; ++ct)
            bf[ct] = *(const short8v*)&Bs[ct * 16 + ll][lg * 8];
        __builtin_amdgcn_s_setprio(1);
        #pragma unroll
        for (int ct = 0; ct < 4; ++ct)
            acc[ct] = __builtin_amdgcn_mfma_f32_16x16x32_bf16(af, bf[ct], acc[ct], 0, 0, 0);
        __builtin_amdgcn_s_setprio(0);
    }

    #pragma unroll
    for (int ct = 0; ct < 4; ++ct) {
        #pragma unroll
        for (int r = 0; r < 4; ++r) {
            int row = r0 + w * 16 + lg * 4 + r;
            int col = c0 + ct * 16 + ll;
            float val = acc[ct][r];
            if (MODE == 0) {
                ((ushort*)C)[(size_t)row * QCOLS_ + col] = f2b(val * 0.125f);
            } else {
                int b = row >> 11;
                int j = (row & 2047) + NUM_MEM_;
                if (col < DH_)
                    ((ushort*)C)[((size_t)(b * JPAD_) + j) * DH_ + col] = f2b(val);
                else
                    ((ushort*)C2)[((size_t)(b * DH_) + (col - DH_)) * JPAD_ + j] = f2b(val);
            }
        }
    }
    __syncthreads();
}

// ---------------- phase 5: out-proj GEMM body (BM=128, BK=32, f32 out) ----------------
static __device__ __forceinline__ void gemm_out_body(char* smem,
                                                     const ushort* __restrict__ A,
                                                     const ushort* __restrict__ Bt,
                                                     float* __restrict__ C,
                                                     int bx, int by) {
    ushort (*As)[40] = (ushort(*)[40])smem;
    ushort (*Bs)[40] = (ushort(*)[40])(smem + 128 * 40 * 2);
    const int K = QCOLS_;
    int tid = threadIdx.x;
    int w = tid >> 6, l = tid & 63, lg = l >> 4, ll = l & 15;
    int r0 = by * 128, c0 = bx * 64;

    int arow = tid >> 2;
    int achk = (tid & 3) * 8;
    const ushort* Ap  = A + (size_t)(r0 + arow) * K + achk;
    const ushort* Ap2 = Ap + (size_t)64 * K;
    const ushort* Bp  = Bt + (size_t)(c0 + arow) * K + achk;

    int4 a0 = *(const int4*)Ap;
    int4 a1 = *(const int4*)Ap2;
    int4 b0 = *(const int4*)Bp;

    f32x4 acc[2][4] = {};

    int nk = K / 32;
    for (int ks = 0; ks < nk; ++ks) {
        __syncthreads();
        *(int4*)&As[arow][achk]      = a0;
        *(int4*)&As[arow + 64][achk] = a1;
        *(int4*)&Bs[arow][achk]      = b0;
        __syncthreads();
        int kn = (ks + 1 < nk) ? (ks + 1) * 32 : 0;
        a0 = *(const int4*)(Ap + kn);
        a1 = *(const int4*)(Ap2 + kn);
        b0 = *(const int4*)(Bp + kn);
        short8v af[2], bf[4];
        af[0] = *(const short8v*)&As[w * 32 + ll][lg * 8];
        af[1] = *(const short8v*)&As[w * 32 + 16 + ll][lg * 8];
        #pragma unroll
        for (int ct = 0; ct < 4; ++ct)
            bf[ct] = *(const short8v*)&Bs[ct * 16 + ll][lg * 8];
        __builtin_amdgcn_s_setprio(1);
        #pragma unroll
        for (int rt = 0; rt < 2; ++rt)
            #pragma unroll
            for (int ct = 0; ct < 4; ++ct)
                acc[rt][ct] = __builtin_amdgcn_mfma_f32_16x16x32_bf16(af[rt], bf[ct], acc[rt][ct], 0, 0, 0);
        __builtin_amdgcn_s_setprio(0);
    }

    #pragma unroll
    for (int rt = 0; rt < 2; ++rt)
        #pragma unroll
        for (int ct = 0; ct < 4; ++ct)
            #pragma unroll
            for (int r = 0; r < 4; ++r) {
                int row = r0 + w * 32 + rt * 16 + lg * 4 + r;
                int col = c0 + ct * 16 + ll;
                C[(size_t)row * DIM_ + col] = acc[rt][ct][r];
            }
    __syncthreads();
}

// ---------------- phase 3: flash attention body (KV-split, swapped-QK^T) ----------------
static __device__ __forceinline__ void fattn_body(char* smem, int cid,
                                                  const ushort* __restrict__ qb,
                                                  const ushort* __restrict__ Kb,
                                                  const ushort* __restrict__ Vt,
                                                  const float* __restrict__ bias,
                                                  const ushort* __restrict__ amask,
                                                  ushort* __restrict__ part_O,
                                                  float* __restrict__ part_ml,
                                                  ushort* __restrict__ attn_ob) {
    ushort (*Ks)[72] = (ushort(*)[72])smem;
    ushort (*Vs)[72] = (ushort(*)[72])(smem + 64 * 72 * 2);
    ushort (*Bb)[68] = (ushort(*)[68])(smem + 2 * 64 * 72 * 2);

    int bh  = cid / CHUNKS_PER_BH_;
    int rem = cid - bh * CHUNKS_PER_BH_;
    int b = bh >> 3, h = bh & 7;
    int qt = 0, ci = 0;
    {
        int cum = 0;
        #pragma unroll 1
        for (int t = 0; t < 32; ++t) {
            int c = (t + 10) / 9;            // ceil((t+2)/9)
            if (rem < cum + c) { qt = t; ci = rem - cum; break; }
            cum += c;
        }
    }
    int nt = qt + 2;
    int nc = (qt + 10) / 9;
    int t0 = ci * nt / nc;
    int t1 = (ci + 1) * nt / nc;
    int q0 = qt * 64;

    int tid = threadIdx.x;
    int w  = tid >> 6;
    int l  = tid & 63;
    int lg = l >> 4;
    int ll = l & 15;
    int i_row = q0 + w * 16 + ll;

    short8v aq0, aq1;
    {
        const ushort* qp = qb + ((size_t)(b * N_ + i_row)) * QCOLS_ + h * DH_;
        aq0 = *(const short8v*)(qp + lg * 8);
        aq1 = *(const short8v*)(qp + 32 + lg * 8);
    }

    int trow = tid >> 5;
    int tpc  = tid & 31;
    const float*  bias_rb = bias + ((size_t)h * N_ + q0 + trow) * N_;
    const ushort* am_row  = amask + (size_t)b * JPAD_;

    int sr = tid >> 3, sc = (tid & 7) * 8;
    const ushort* KbB = Kb + (size_t)b * JPAD_ * DH_;
    const ushort* VtB = Vt + (size_t)b * DH_ * JPAD_;

    int srcA = ((l & 16) << 1) + ll;
    int srcB = srcA + 16;
    bool hi = (l & 32) != 0;

    int jp0 = t0 * 64;
    int4 kr0 = *(const int4*)(KbB + (size_t)(jp0 + sr) * DH_ + sc);
    int4 kr1 = *(const int4*)(KbB + (size_t)(jp0 + sr + 32) * DH_ + sc);
    int4 vr0 = *(const int4*)(VtB + (size_t)sr * JPAD_ + jp0 + sc);
    int4 vr1 = *(const int4*)(VtB + (size_t)(sr + 32) * JPAD_ + jp0 + sc);

    uint bbc[8];
    {
        int j_e = jp0 + 2 * tpc;
        int sj  = j_e - NUM_MEM_;
        int sjc = sj < 0 ? 0 : (sj > N_ - 2 ? N_ - 2 : sj);
        uint am2 = *(const uint*)(am_row + j_e);
        float amf0 = b2f_lo(am2), amf1 = b2f_hi(am2);
        #pragma unroll
        for (int p = 0; p < 8; ++p) {
            float2 bv = *(const float2*)(bias_rb + (size_t)(8 * p) * N_ + sjc);
            int i_s = q0 + trow + 8 * p;
            float v0 = (j_e     < NUM_MEM_) ? 0.f : bv.x + amf0;
            float v1 = (j_e + 1 < NUM_MEM_) ? 0.f : bv.y + amf1;
            v0 = (j_e     <= i_s + NUM_MEM_) ? v0 : -1e30f;
            v1 = (j_e + 1 <= i_s + NUM_MEM_) ? v1 : -1e30f;
            bbc[p] = pk2(v0, v1);
        }
    }

    f32x4 oacc[4] = {};
    float mrow1 = -1e30f, lsum1 = 0.f;

    for (int jt = t0; jt < t1; ++jt) {
        __syncthreads();
        *(int4*)&Ks[sr][sc]      = kr0;
        *(int4*)&Ks[sr + 32][sc] = kr1;
        *(int4*)&Vs[sr][sc]      = vr0;
        *(int4*)&Vs[sr + 32][sc] = vr1;
        #pragma unroll
        for (int p = 0; p < 8; ++p)
            *(uint*)&Bb[trow + 8 * p][2 * tpc] = bbc[p];
        __syncthreads();

        int jn0 = (jt + 1 < t1 ? jt + 1 : jt) * 64;
        kr0 = *(const int4*)(KbB + (size_t)(jn0 + sr) * DH_ + sc);
        kr1 = *(const int4*)(KbB + (size_t)(jn0 + sr + 32) * DH_ + sc);
        vr0 = *(const int4*)(VtB + (size_t)sr * JPAD_ + jn0 + sc);
        vr1 = *(const int4*)(VtB + (size_t)(sr + 32) * JPAD_ + jn0 + sc);
        int j_e = jn0 + 2 * tpc;
        int sj  = j_e - NUM_MEM_;
        int sjc = sj < 0 ? 0 : (sj > N_ - 2 ? N_ - 2 : sj);
        uint am2n = *(const uint*)(am_row + j_e);
        float2 bvn[8];
        #pragma unroll
        for (int p = 0; p < 8; ++p)
            bvn[p] = *(const float2*)(bias_rb + (size_t)(8 * p) * N_ + sjc);

        float s[4][4];
        #pragma unroll
        for (int ct = 0; ct < 4; ++ct) {
            f32x4 acc = {};
            short8v bk0 = *(const short8v*)&Ks[ct * 16 + ll][lg * 8];
            short8v bk1 = *(const short8v*)&Ks[ct * 16 + ll][32 + lg * 8];
            __builtin_amdgcn_s_setprio(1);
            acc = __builtin_amdgcn_mfma_f32_16x16x32_bf16(bk0, aq0, acc, 0, 0, 0);
            acc = __builtin_amdgcn_mfma_f32_16x16x32_bf16(bk1, aq1, acc, 0, 0, 0);
            __builtin_amdgcn_s_setprio(0);
            uint2 ub = *(const uint2*)&Bb[w * 16 + ll][ct * 16 + lg * 4];
            s[ct][0] = acc[0] + b2f_lo(ub.x);
            s[ct][1] = acc[1] + b2f_hi(ub.x);
            s[ct][2] = acc[2] + b2f_lo(ub.y);
            s[ct][3] = acc[3] + b2f_hi(ub.y);
        }

        float m01 = fmaxf(fmaxf(s[0][0], s[0][1]), fmaxf(s[0][2], s[0][3]));
        float m23 = fmaxf(fmaxf(s[1][0], s[1][1]), fmaxf(s[1][2], s[1][3]));
        float m45 = fmaxf(fmaxf(s[2][0], s[2][1]), fmaxf(s[2][2], s[2][3]));
        float m67 = fmaxf(fmaxf(s[3][0], s[3][1]), fmaxf(s[3][2], s[3][3]));
        float m = fmaxf(fmaxf(m01, m23), fmaxf(m45, m67));
        m = fmaxf(m, __shfl_xor(m, 16));
        m = fmaxf(m, __shfl_xor(m, 32));
        float mn = fmaxf(mrow1, m);
        float scl = __expf(mrow1 - mn);
        mrow1 = mn;

        float ps = 0.f;
        #pragma unroll
        for (int ct = 0; ct < 4; ++ct)
            #pragma unroll
            for (int r = 0; r < 4; ++r) {
                float p = __expf(s[ct][r] - mn);
                s[ct][r] = p;
                ps += p;
            }
        ps += __shfl_xor(ps, 16);
        ps += __shfl_xor(ps, 32);
        lsum1 = lsum1 * scl + ps;

        uint pux[4], puy[4];
        #pragma unroll
        for (int ct = 0; ct < 4; ++ct) {
            pux[ct] = pk2(s[ct][0], s[ct][1]);
            puy[ct] = pk2(s[ct][2], s[ct][3]);
        }
        #pragma unroll
        for (int dt = 0; dt < 4; ++dt)
            #pragma unroll
            for (int r = 0; r < 4; ++r) oacc[dt][r] *= scl;

        #pragma unroll
        for (int c = 0; c < 2; ++c) {
            int cl = 2 * c, ch = 2 * c + 1;
            uint xA_l = (uint)__shfl((int)pux[cl], srcA);
            uint xA_h = (uint)__shfl((int)pux[ch], srcA);
            uint yA_l = (uint)__shfl((int)puy[cl], srcA);
            uint yA_h = (uint)__shfl((int)puy[ch], srcA);
            uint xB_l = (uint)__shfl((int)pux[cl], srcB);
            uint xB_h = (uint)__shfl((int)pux[ch], srcB);
            uint yB_l = (uint)__shfl((int)puy[cl], srcB);
            uint yB_h = (uint)__shfl((int)puy[ch], srcB);
            uint uu[4];
            uu[0] = hi ? xA_h : xA_l;
            uu[1] = hi ? yA_h : yA_l;
            uu[2] = hi ? xB_h : xB_l;
            uu[3] = hi ? yB_h : yB_l;
            short8v ptf = *(const short8v*)uu;
            __builtin_amdgcn_s_setprio(1);
            #pragma unroll
            for (int dt = 0; dt < 4; ++dt) {
                short8v bv = *(const short8v*)&Vs[dt * 16 + ll][c * 32 + lg * 8];
                oacc[dt] = __builtin_amdgcn_mfma_f32_16x16x32_bf16(bv, ptf, oacc[dt], 0, 0, 0);
            }
            __builtin_amdgcn_s_setprio(0);
        }

        {
            float amf0 = b2f_lo(am2n), amf1 = b2f_hi(am2n);
            #pragma unroll
            for (int p = 0; p < 8; ++p) {
                int i_s = q0 + trow + 8 * p;
                float v0 = (j_e     < NUM_MEM_) ? 0.f : bvn[p].x + amf0;
                float v1 = (j_e + 1 < NUM_MEM_) ? 0.f : bvn[p].y + amf1;
                v0 = (j_e     <= i_s + NUM_MEM_) ? v0 : -1e30f;
                v1 = (j_e + 1 <= i_s + NUM_MEM_) ? v1 : -1e30f;
                bbc[p] = pk2(v0, v1);
            }
        }
    }

    if (nc == 1) {
        float inv = 1.f / lsum1;
        ushort* dst = attn_ob + ((size_t)(b * N_ + i_row)) * QCOLS_ + h * DH_;
        #pragma unroll
        for (int dt = 0; dt < 4; ++dt) {
            uint2 pu;
            pu.x = pk2(oacc[dt][0] * inv, oacc[dt][1] * inv);
            pu.y = pk2(oacc[dt][2] * inv, oacc[dt][3] * inv);
            *(uint2*)(dst + dt * 16 + lg * 4) = pu;
        }
    } else {
        int slot = (bh * 32 + qt) * 4 + ci;
        ushort* po = part_O + (size_t)slot * 4096;
        #pragma unroll
        for (int dt = 0; dt < 4; ++dt) {
            uint2 pu;
            pu.x = pk2(oacc[dt][0], oacc[dt][1]);
            pu.y = pk2(oacc[dt][2], oacc[dt][3]);
            *(uint2*)&po[(w * 16 + ll) * 64 + dt * 16 + lg * 4] = pu;
        }
        if (lg == 0) {
            part_ml[(size_t)slot * 128 + (w * 16 + ll) * 2]     = mrow1;
            part_ml[(size_t)slot * 128 + (w * 16 + ll) * 2 + 1] = lsum1;
        }
    }
    __syncthreads();
}

// ---------------- phase 4: merge body (multi-chunk strips only) ----------------
static __device__ __forceinline__ void merge_body(int bid,
                                                  const ushort* __restrict__ part_O,
                                                  const float* __restrict__ part_ml,
                                                  ushort* __restrict__ attn_ob) {
    int qt = bid & 31;
    int nc = (qt + 10) / 9;
    if (nc < 2) return;
    int bh = bid >> 5;
    int b = bh >> 3, h = bh & 7;
    int tid = threadIdx.x;
    int row = tid >> 2;
    int dseg = (tid & 3) * 16;
    int slot0 = bid * 4;

    float M = -1e30f;
    #pragma unroll
    for (int c = 0; c < 4; ++c) {
        if (c >= nc) break;
        M = fmaxf(M, part_ml[(size_t)(slot0 + c) * 128 + row * 2]);
    }
    float den = 0.f;
    float num[16] = {};
    #pragma unroll
    for (int c = 0; c < 4; ++c) {
        if (c >= nc) break;
        float m_c = part_ml[(size_t)(slot0 + c) * 128 + row * 2];
        float l_c = part_ml[(size_t)(slot0 + c) * 128 + row * 2 + 1];
        float wgt = __expf(m_c - M);
        den += wgt * l_c;
        const uint4* src = (const uint4*)(part_O + (size_t)(slot0 + c) * 4096 + row * 64 + dseg);
        uint4 v0 = src[0];
        uint4 v1 = src[1];
        uint uu[8] = { v0.x, v0.y, v0.z, v0.w, v1.x, v1.y, v1.z, v1.w };
        #pragma unroll
        for (int e = 0; e < 8; ++e) {
            num[e * 2 + 0] += wgt * b2f_lo(uu[e]);
            num[e * 2 + 1] += wgt * b2f_hi(uu[e]);
        }
    }
    float inv = 1.f / den;
    ushort o[16];
    #pragma unroll
    for (int e = 0; e < 16; ++e) o[e] = f2b(num[e] * inv);
    int i = qt * 64 + row;
    ushort* dst = attn_ob + ((size_t)(b * N_ + i)) * QCOLS_ + h * DH_ + dseg;
    *(int4*)dst = *(int4*)o;
    *(int4*)(dst + 8) = *(int4*)(o + 8);
}

// ---------------- the cooperative mega-kernel ----------------
__global__ __launch_bounds__(256, 4) void mega_kernel(const float* __restrict__ x,
                                                      const float* __restrict__ bias,
                                                      const float* __restrict__ gamma,
                                                      const float* __restrict__ Wq,
                                                      const float* __restrict__ Wkv,
                                                      const float* __restrict__ Wout,
                                                      const float* __restrict__ mem_kv,
                                                      const int* __restrict__ mask,
                                                      float* __restrict__ out,
                                                      ushort* __restrict__ xb,
                                                      ushort* __restrict__ xnb,
                                                      ushort* __restrict__ qb,
                                                      ushort* __restrict__ attn_ob,
                                                      ushort* __restrict__ Kb,
                                                      ushort* __restrict__ Vt,
                                                      ushort* __restrict__ Wqt,
                                                      ushort* __restrict__ Wkvt,
                                                      ushort* __restrict__ Woutt,
                                                      ushort* __restrict__ amask,
                                                      ushort* __restrict__ part_O,
                                                      float* __restrict__ part_ml) {
    cg::grid_group grid = cg::this_grid();
    __shared__ __align__(16) char smem[SMEM_BYTES];
    int nb = gridDim.x;

    // Phase 1: LN + prep (4753 units)
    for (int u = blockIdx.x; u < ROWS_ + 657; u += nb) {
        if (u < ROWS_) ln_body(smem, u, x, gamma, xb, xnb);
        else prep_body(u - ROWS_, Wq, Wkv, Wout, mem_kv, mask, Wqt, Wkvt, Woutt, Kb, Vt, amask);
    }
    grid.sync();

    // Phase 2: Q-proj (512) + KV-proj (128)
    for (int u = blockIdx.x; u < 640; u += nb) {
        if (u < 512) gemm64_body<0>(smem, xnb, Wqt, qb, nullptr, DIM_, u & 7, u >> 3);
        else {
            int r = u - 512;
            gemm64_body<1>(smem, xb, Wkvt, Kb, Vt, DIM_, r & 1, r >> 1);
        }
    }
    grid.sync();

    // Phase 3: flash attention (1232 chunk units)
    for (int u = blockIdx.x; u < 16 * CHUNKS_PER_BH_; u += nb)
        fattn_body(smem, u, qb, Kb, Vt, bias, amask, part_O, part_ml, attn_ob);
    grid.sync();

    // Phase 4: merge (512 units)
    for (int u = blockIdx.x; u < 512; u += nb)
        merge_body(u, part_O, part_ml, attn_ob);
    grid.sync();

    // Phase 5: out-proj (512 units: 16 cols x 32 row-tiles)
    for (int u = blockIdx.x; u < 512; u += nb)
        gemm_out_body(smem, attn_ob, Woutt, out, u & 15, u >> 4);
}

extern "C" void kernel_launch(void* const* d_in, const int* in_sizes, int n_in,
                              void* d_out, int out_size, void* d_ws, size_t ws_size,
                              hipStream_t stream) {
    const float* x         = (const float*)d_in[0];
    const float* attn_bias = (const float*)d_in[1];
    const float* gamma     = (const float*)d_in[2];
    const float* Wq        = (const float*)d_in[3];
    const float* Wkv       = (const float*)d_in[4];
    const float* mem_kv    = (const float*)d_in[5];
    const float* Wout      = (const float*)d_in[6];
    const int*   mask      = (const int*)d_in[7];
    float* out = (float*)d_out;

    char* wsb = (char*)d_ws;
    ushort* xb      = (ushort*)wsb;                    // 8 MB
    ushort* xnb     = (ushort*)(wsb + (8u  << 20));    // 8 MB
    ushort* qb      = (ushort*)(wsb + (16u << 20));    // 4 MB
    ushort* attn_ob = (ushort*)(wsb + (20u << 20));    // 4 MB
    ushort* Kb      = (ushort*)(wsb + (24u << 20));    // 0.56 MB
    ushort* Vt      = (ushort*)(wsb + (25u << 20));    // 0.56 MB
    ushort* Wqt     = (ushort*)(wsb + (26u << 20));    // 1 MB
    ushort* Wkvt    = (ushort*)(wsb + (27u << 20));    // 0.25 MB
    ushort* Woutt   = (ushort*)(wsb + (28u << 20));    // 1 MB
    ushort* amask   = (ushort*)(wsb + (29u << 20));    // 8.5 KB
    ushort* part_O  = (ushort*)(wsb + (32u << 20));    // 16 MB
    float*  part_ml = (float*)(wsb + (64u << 20));     // 1 MB

    // conservative co-resident grid: query occupancy, cap at 4/CU x 256 CUs
    int blocks_per_cu = 4;
    (void)hipOccupancyMaxActiveBlocksPerMultiprocessor(&blocks_per_cu,
            reinterpret_cast<const void*>(mega_kernel), 256, 0);
    if (blocks_per_cu < 1) blocks_per_cu = 1;
    if (blocks_per_cu > 4) blocks_per_cu = 4;
    int grid = blocks_per_cu * 256;

    void* kargs[] = { (void*)&x, (void*)&attn_bias, (void*)&gamma, (void*)&Wq, (void*)&Wkv,
                      (void*)&Wout, (void*)&mem_kv, (void*)&mask, (void*)&out,
                      (void*)&xb, (void*)&xnb, (void*)&qb, (void*)&attn_ob, (void*)&Kb, (void*)&Vt,
                      (void*)&Wqt, (void*)&Wkvt, (void*)&Woutt, (void*)&amask,
                      (void*)&part_O, (void*)&part_ml };
    hipLaunchCooperativeKernel(reinterpret_cast<void*>(mega_kernel),
                               dim3(grid), dim3(256), kargs, 0, stream);
}

// Round 17
// 94.820 us; speedup vs baseline: 4.0673x; 4.0673x over previous
//
#include <hip/hip_runtime.h>
#include <hip/hip_bf16.h>
#include <float.h>

#define B_ 2
#define N_ 2048
#define DIM_ 1024
#define HEADS_ 8
#define DH_ 64
#define NUM_MEM_ 4
#define ROWS_ (B_ * N_)          // 4096
#define QCOLS_ (HEADS_ * DH_)    // 512
#define JTOT_ (N_ + NUM_MEM_)    // 2052
#define JPAD_ 2176               // 17 * 128
#define CHUNKS_PER_BH_ 77        // sum over qt of ceil((qt+2)/9)

typedef __attribute__((ext_vector_type(8))) short short8v;
typedef __attribute__((ext_vector_type(4))) float f32x4;

static __device__ __forceinline__ ushort f2b(float f) {
    __hip_bfloat16 hb = __float2bfloat16(f);
    return *(ushort*)&hb;
}
static __device__ __forceinline__ uint pk2(float a, float b) {
    return ((uint)f2b(b) << 16) | (uint)f2b(a);
}
static __device__ __forceinline__ float b2f_lo(uint u) {
    union { uint x; float f; } c; c.x = u << 16; return c.f;
}
static __device__ __forceinline__ float b2f_hi(uint u) {
    union { uint x; float f; } c; c.x = u & 0xffff0000u; return c.f;
}

// ---------------- fused: LayerNorm+cast  |  weight transposes + KV seed + amask ----------------
static __device__ __forceinline__ void wtrans_body(const float* __restrict__ W,
                                                   ushort* __restrict__ Wt,
                                                   int K, int N, int t) {
    int n = t % N;
    int k0 = (t / N) * 8;
    ushort u[8];
    #pragma unroll
    for (int j = 0; j < 8; ++j) u[j] = f2b(W[(size_t)(k0 + j) * N + n]);
    *(int4*)(Wt + (size_t)n * K + k0) = *(int4*)u;
}

__global__ __launch_bounds__(256) void ln_prep_kernel(const float* __restrict__ x,
                                                      const float* __restrict__ gamma,
                                                      const float* __restrict__ Wq,
                                                      const float* __restrict__ Wkv,
                                                      const float* __restrict__ Wout,
                                                      const float* __restrict__ mem_kv,
                                                      const int* __restrict__ mask,
                                                      ushort* __restrict__ xb,
                                                      ushort* __restrict__ xnb,
                                                      ushort* __restrict__ Wqt,
                                                      ushort* __restrict__ Wkvt,
                                                      ushort* __restrict__ Woutt,
                                                      ushort* __restrict__ Kb,
                                                      ushort* __restrict__ Vt,
                                                      ushort* __restrict__ amask) {
    int bid0 = blockIdx.x;
    if (bid0 < ROWS_) {
        int row = bid0;
        const float4 v = ((const float4*)(x + (size_t)row * DIM_))[threadIdx.x];
        float s  = v.x + v.y + v.z + v.w;
        float s2 = v.x * v.x + v.y * v.y + v.z * v.z + v.w * v.w;
        #pragma unroll
        for (int off = 32; off > 0; off >>= 1) {
            s  += __shfl_down(s, off);
            s2 += __shfl_down(s2, off);
        }
        __shared__ float ws1[4], ws2[4];
        int lane = threadIdx.x & 63, wid = threadIdx.x >> 6;
        if (lane == 0) { ws1[wid] = s; ws2[wid] = s2; }
        __syncthreads();
        float tot  = ws1[0] + ws1[1] + ws1[2] + ws1[3];
        float tot2 = ws2[0] + ws2[1] + ws2[2] + ws2[3];
        float mu  = tot * (1.0f / DIM_);
        float var = tot2 * (1.0f / DIM_) - mu * mu;
        float rs  = rsqrtf(var + 1e-5f);
        const float4 g = ((const float4*)gamma)[threadIdx.x];
        float vv[4] = {v.x, v.y, v.z, v.w};
        float gg[4] = {g.x, g.y, g.z, g.w};
        ushort xo[4], xno[4];
        #pragma unroll
        for (int j = 0; j < 4; ++j) {
            xo[j]  = f2b(vv[j]);
            xno[j] = f2b((vv[j] - mu) * rs * gg[j]);
        }
        *(int2*)(xb  + (size_t)row * DIM_ + threadIdx.x * 4) = *(int2*)xo;
        *(int2*)(xnb + (size_t)row * DIM_ + threadIdx.x * 4) = *(int2*)xno;
        return;
    }
    int bid = bid0 - ROWS_;
    int tid = threadIdx.x;
    if (bid < 256) {
        wtrans_body(Wq, Wqt, DIM_, QCOLS_, bid * 256 + tid);
    } else if (bid < 320) {
        wtrans_body(Wkv, Wkvt, DIM_, 2 * DH_, (bid - 256) * 256 + tid);
    } else if (bid < 576) {
        wtrans_body(Wout, Woutt, QCOLS_, DIM_, (bid - 320) * 256 + tid);
    } else if (bid < 640) {
        int t = (bid - 576) * 256 + tid;
        int d  = t & 63;
        int ji = (t >> 6) & 127;
        int b  = t >> 13;
        int j  = (ji < NUM_MEM_) ? ji : (2048 + ji);
        float kv_ = 0.f, vv = 0.f;
        if (ji < NUM_MEM_) {
            kv_ = mem_kv[ji * DH_ + d];
            vv  = mem_kv[NUM_MEM_ * DH_ + ji * DH_ + d];
        }
        Kb[((size_t)(b * JPAD_) + j) * DH_ + d] = f2b(kv_);
        Vt[((size_t)(b * DH_) + d) * JPAD_ + j] = f2b(vv);
    } else {
        int t = (bid - 640) * 256 + tid;
        if (t < B_ * JPAD_) {
            int b = t / JPAD_;
            int j = t % JPAD_;
            float v;
            if (j < NUM_MEM_) v = 0.f;
            else if (j < JTOT_) v = mask[b * N_ + (j - NUM_MEM_)] ? 0.f : -1e30f;
            else v = -1e30f;
            amask[(size_t)b * JPAD_ + j] = f2b(v);
        }
    }
}

// ---------------- bf16 MFMA GEMM body, BM=64, BK=32 (device fn, shared LDS) ----------------
// MODE 0: qb (bf16, *0.125)   MODE 1: Kb / Vt scatter
template<int MODE>
static __device__ __forceinline__ void gemm64_body(ushort (*As)[40], ushort (*Bs)[40],
                                                   const ushort* __restrict__ A,
                                                   const ushort* __restrict__ Bt,
                                                   void* __restrict__ C,
                                                   void* __restrict__ C2,
                                                   int N, int K, int bx, int by) {
    int tid = threadIdx.x;
    int w = tid >> 6, l = tid & 63, lg = l >> 4, ll = l & 15;
    int r0 = by * 64, c0 = bx * 64;

    int arow = tid >> 2;           // 0..63
    int achk = (tid & 3) * 8;      // 0,8,16,24
    const ushort* Ap = A + (size_t)(r0 + arow) * K + achk;
    const ushort* Bp = Bt + (size_t)(c0 + arow) * K + achk;

    int4 a0 = *(const int4*)Ap;
    int4 b0 = *(const int4*)Bp;

    f32x4 acc[4] = {};

    int nk = K / 32;
    for (int ks = 0; ks < nk; ++ks) {
        __syncthreads();
        *(int4*)&As[arow][achk] = a0;
        *(int4*)&Bs[arow][achk] = b0;
        __syncthreads();
        int kn = (ks + 1 < nk) ? (ks + 1) * 32 : 0;   // wrap: dummy re-read
        a0 = *(const int4*)(Ap + kn);
        b0 = *(const int4*)(Bp + kn);
        short8v af, bf[4];
        af = *(const short8v*)&As[w * 16 + ll][lg * 8];
        #pragma unroll
        for (int ct = 0; ct < 4; ++ct)
            bf[ct] = *(const short8v*)&Bs[ct * 16 + ll][lg * 8];
        __builtin_amdgcn_s_setprio(1);
        #pragma unroll
        for (int ct = 0; ct < 4; ++ct)
            acc[ct] = __builtin_amdgcn_mfma_f32_16x16x32_bf16(af, bf[ct], acc[ct], 0, 0, 0);
        __builtin_amdgcn_s_setprio(0);
    }

    #pragma unroll
    for (int ct = 0; ct < 4; ++ct) {
        #pragma unroll
        for (int r = 0; r < 4; ++r) {
            int row = r0 + w * 16 + lg * 4 + r;
            int col = c0 + ct * 16 + ll;
            float val = acc[ct][r];
            if (MODE == 0) {
                ((ushort*)C)[(size_t)row * QCOLS_ + col] = f2b(val * 0.125f);
            } else {
                int b = row >> 11;
                int j = (row & 2047) + NUM_MEM_;
                if (col < DH_)
                    ((ushort*)C)[((size_t)(b * JPAD_) + j) * DH_ + col] = f2b(val);
                else
                    ((ushort*)C2)[((size_t)(b * DH_) + (col - DH_)) * JPAD_ + j] = f2b(val);
            }
        }
    }
}

// fused Q-proj (512 blocks) + KV-proj (128 blocks)
__global__ __launch_bounds__(256) void gemm01_kernel(const ushort* __restrict__ xnb,
                                                     const ushort* __restrict__ Wqt,
                                                     ushort* __restrict__ qb,
                                                     const ushort* __restrict__ xb,
                                                     const ushort* __restrict__ Wkvt,
                                                     ushort* __restrict__ Kb,
                                                     ushort* __restrict__ Vt) {
    __shared__ ushort As[64][40];
    __shared__ ushort Bs[64][40];
    int bid = blockIdx.x;
    if (bid < 512) {
        gemm64_body<0>(As, Bs, xnb, Wqt, qb, nullptr, QCOLS_, DIM_, bid & 7, bid >> 3);
    } else {
        int r = bid - 512;
        gemm64_body<1>(As, Bs, xb, Wkvt, Kb, Vt, 2 * DH_, DIM_, r & 1, r >> 1);
    }
}

// ---------------- standalone out-proj GEMM (BM=128, BK=32, f32 out) ----------------
__global__ __launch_bounds__(256) void gemm_out_kernel(const ushort* __restrict__ A,
                                                       const ushort* __restrict__ Bt,
                                                       float* __restrict__ C,
                                                       int M, int N, int K) {
    __shared__ ushort As[128][40];
    __shared__ ushort Bs[64][40];
    int tid = threadIdx.x;
    int w = tid >> 6, l = tid & 63, lg = l >> 4, ll = l & 15;
    int r0 = blockIdx.y * 128, c0 = blockIdx.x * 64;

    int arow = tid >> 2;
    int achk = (tid & 3) * 8;
    const ushort* Ap  = A + (size_t)(r0 + arow) * K + achk;
    const ushort* Ap2 = Ap + (size_t)64 * K;
    const ushort* Bp  = Bt + (size_t)(c0 + arow) * K + achk;

    int4 a0 = *(const int4*)Ap;
    int4 a1 = *(const int4*)Ap2;
    int4 b0 = *(const int4*)Bp;

    f32x4 acc[2][4] = {};

    int nk = K / 32;
    for (int ks = 0; ks < nk; ++ks) {
        __syncthreads();
        *(int4*)&As[arow][achk]      = a0;
        *(int4*)&As[arow + 64][achk] = a1;
        *(int4*)&Bs[arow][achk]      = b0;
        __syncthreads();
        int kn = (ks + 1 < nk) ? (ks + 1) * 32 : 0;
        a0 = *(const int4*)(Ap + kn);
        a1 = *(const int4*)(Ap2 + kn);
        b0 = *(const int4*)(Bp + kn);
        short8v af[2], bf[4];
        af[0] = *(const short8v*)&As[w * 32 + ll][lg * 8];
        af[1] = *(const short8v*)&As[w * 32 + 16 + ll][lg * 8];
        #pragma unroll
        for (int ct = 0; ct < 4; ++ct)
            bf[ct] = *(const short8v*)&Bs[ct * 16 + ll][lg * 8];
        __builtin_amdgcn_s_setprio(1);
        #pragma unroll
        for (int rt = 0; rt < 2; ++rt)
            #pragma unroll
            for (int ct = 0; ct < 4; ++ct)
                acc[rt][ct] = __builtin_amdgcn_mfma_f32_16x16x32_bf16(af[rt], bf[ct], acc[rt][ct], 0, 0, 0);
        __builtin_amdgcn_s_setprio(0);
    }

    #pragma unroll
    for (int rt = 0; rt < 2; ++rt)
        #pragma unroll
        for (int ct = 0; ct < 4; ++ct)
            #pragma unroll
            for (int r = 0; r < 4; ++r) {
                int row = r0 + w * 32 + rt * 16 + lg * 4 + r;
                int col = c0 + ct * 16 + ll;
                C[(size_t)row * DIM_ + col] = acc[rt][ct][r];
            }
}

// ---------------- flash attention, KV-split, swapped-QK^T, shuffle PV feed ----------------
// LPT dispatch: longest chunks (high qt) launch first -> shorter kernel tail
__global__ __launch_bounds__(256, 4) void fattn_split_kernel(const ushort* __restrict__ qb,
                                                             const ushort* __restrict__ Kb,
                                                             const ushort* __restrict__ Vt,
                                                             const float* __restrict__ bias,
                                                             const ushort* __restrict__ amask,
                                                             ushort* __restrict__ part_O,
                                                             float* __restrict__ part_ml,
                                                             ushort* __restrict__ attn_ob) {
    __shared__ ushort Ks[64][72];        // K tile (j rows, d cols)
    __shared__ ushort Vs[64][72];        // V^T tile (d rows, j cols)
    __shared__ ushort Bb[64][68];        // folded bias+mask+causal, bf16 [i-row][j]

    // decode chunk id -> (b, h, qt, ci); rem flipped so big-qt chunks go first (LPT)
    int cid = blockIdx.x;
    int bh  = cid / CHUNKS_PER_BH_;
    int rem = cid - bh * CHUNKS_PER_BH_;
    rem = CHUNKS_PER_BH_ - 1 - rem;      // LPT flip
    int b = bh >> 3, h = bh & 7;
    int qt = 0, ci = 0;
    {
        int cum = 0;
        #pragma unroll 1
        for (int t = 0; t < 32; ++t) {
            int c = (t + 10) / 9;            // ceil((t+2)/9)
            if (rem < cum + c) { qt = t; ci = rem - cum; break; }
            cum += c;
        }
    }
    int nt = qt + 2;
    int nc = (qt + 10) / 9;
    int t0 = ci * nt / nc;
    int t1 = (ci + 1) * nt / nc;
    int q0 = qt * 64;

    int tid = threadIdx.x;
    int w  = tid >> 6;
    int l  = tid & 63;
    int lg = l >> 4;
    int ll = l & 15;
    int i_row = q0 + w * 16 + ll;       // this lane's q-row (owns it fully)

    // Q fragment (B operand): k = lg*8 + reg, col = ll
    short8v aq0, aq1;
    {
        const ushort* qp = qb + ((size_t)(b * N_ + i_row)) * QCOLS_ + h * DH_;
        aq0 = *(const short8v*)(qp + lg * 8);
        aq1 = *(const short8v*)(qp + 32 + lg * 8);
    }

    // bias stager mapping (coalesced: 32 lanes read 256B of one bias row)
    int trow = tid >> 5;                 // 0..7
    int tpc  = tid & 31;                 // col pair index
    const float*  bias_rb = bias + ((size_t)h * N_ + q0 + trow) * N_;
    const ushort* am_row  = amask + (size_t)b * JPAD_;

    // K/V staging mapping
    int sr = tid >> 3, sc = (tid & 7) * 8;
    const ushort* KbB = Kb + (size_t)b * JPAD_ * DH_;
    const ushort* VtB = Vt + (size_t)b * DH_ * JPAD_;

    // shuffle-PV constants
    int srcA = ((l & 16) << 1) + ll;     // lane holding reg 0..3 of my j-span
    int srcB = srcA + 16;                // lane holding reg 4..7
    bool hi = (l & 32) != 0;             // selects pu[2c+1] vs pu[2c]

    // prologue: prefetch tile t0 (K/V + fold bias)
    int jp0 = t0 * 64;
    int4 kr0 = *(const int4*)(KbB + (size_t)(jp0 + sr) * DH_ + sc);
    int4 kr1 = *(const int4*)(KbB + (size_t)(jp0 + sr + 32) * DH_ + sc);
    int4 vr0 = *(const int4*)(VtB + (size_t)sr * JPAD_ + jp0 + sc);
    int4 vr1 = *(const int4*)(VtB + (size_t)(sr + 32) * JPAD_ + jp0 + sc);

    uint bbc[8];
    {
        int j_e = jp0 + 2 * tpc;
        int sj  = j_e - NUM_MEM_;
        int sjc = sj < 0 ? 0 : (sj > N_ - 2 ? N_ - 2 : sj);
        uint am2 = *(const uint*)(am_row + j_e);
        float amf0 = b2f_lo(am2), amf1 = b2f_hi(am2);
        #pragma unroll
        for (int p = 0; p < 8; ++p) {
            float2 bv = *(const float2*)(bias_rb + (size_t)(8 * p) * N_ + sjc);
            int i_s = q0 + trow + 8 * p;
            float v0 = (j_e     < NUM_MEM_) ? 0.f : bv.x + amf0;
            float v1 = (j_e + 1 < NUM_MEM_) ? 0.f : bv.y + amf1;
            v0 = (j_e     <= i_s + NUM_MEM_) ? v0 : -1e30f;
            v1 = (j_e + 1 <= i_s + NUM_MEM_) ? v1 : -1e30f;
            bbc[p] = pk2(v0, v1);
        }
    }

    f32x4 oacc[4] = {};                  // oacc[dt][r] = O[i_row][dt*16+lg*4+r]
    float mrow1 = -1e30f, lsum1 = 0.f;

    for (int jt = t0; jt < t1; ++jt) {
        __syncthreads();
        *(int4*)&Ks[sr][sc]      = kr0;
        *(int4*)&Ks[sr + 32][sc] = kr1;
        *(int4*)&Vs[sr][sc]      = vr0;
        *(int4*)&Vs[sr + 32][sc] = vr1;
        #pragma unroll
        for (int p = 0; p < 8; ++p)
            *(uint*)&Bb[trow + 8 * p][2 * tpc] = bbc[p];
        __syncthreads();

        // prefetch next tile: K/V + RAW bias loads (issue now, fold after compute)
        int jn0 = (jt + 1 < t1 ? jt + 1 : jt) * 64;
        kr0 = *(const int4*)(KbB + (size_t)(jn0 + sr) * DH_ + sc);
        kr1 = *(const int4*)(KbB + (size_t)(jn0 + sr + 32) * DH_ + sc);
        vr0 = *(const int4*)(VtB + (size_t)sr * JPAD_ + jn0 + sc);
        vr1 = *(const int4*)(VtB + (size_t)(sr + 32) * JPAD_ + jn0 + sc);
        int j_e = jn0 + 2 * tpc;
        int sj  = j_e - NUM_MEM_;
        int sjc = sj < 0 ? 0 : (sj > N_ - 2 ? N_ - 2 : sj);
        uint am2n = *(const uint*)(am_row + j_e);
        float2 bvn[8];
        #pragma unroll
        for (int p = 0; p < 8; ++p)
            bvn[p] = *(const float2*)(bias_rb + (size_t)(8 * p) * N_ + sjc);

        // S^T = K @ Q^T + folded Bb: lane holds 16 j-values for its one q-row
        float s[4][4];
        #pragma unroll
        for (int ct = 0; ct < 4; ++ct) {
            f32x4 acc = {};
            short8v bk0 = *(const short8v*)&Ks[ct * 16 + ll][lg * 8];
            short8v bk1 = *(const short8v*)&Ks[ct * 16 + ll][32 + lg * 8];
            __builtin_amdgcn_s_setprio(1);
            acc = __builtin_amdgcn_mfma_f32_16x16x32_bf16(bk0, aq0, acc, 0, 0, 0);
            acc = __builtin_amdgcn_mfma_f32_16x16x32_bf16(bk1, aq1, acc, 0, 0, 0);
            __builtin_amdgcn_s_setprio(0);
            uint2 ub = *(const uint2*)&Bb[w * 16 + ll][ct * 16 + lg * 4];
            s[ct][0] = acc[0] + b2f_lo(ub.x);
            s[ct][1] = acc[1] + b2f_hi(ub.x);
            s[ct][2] = acc[2] + b2f_lo(ub.y);
            s[ct][3] = acc[3] + b2f_hi(ub.y);
        }

        // in-register online softmax (single owned row; masking folded in Bb)
        float m01 = fmaxf(fmaxf(s[0][0], s[0][1]), fmaxf(s[0][2], s[0][3]));
        float m23 = fmaxf(fmaxf(s[1][0], s[1][1]), fmaxf(s[1][2], s[1][3]));
        float m45 = fmaxf(fmaxf(s[2][0], s[2][1]), fmaxf(s[2][2], s[2][3]));
        float m67 = fmaxf(fmaxf(s[3][0], s[3][1]), fmaxf(s[3][2], s[3][3]));
        float m = fmaxf(fmaxf(m01, m23), fmaxf(m45, m67));
        m = fmaxf(m, __shfl_xor(m, 16));
        m = fmaxf(m, __shfl_xor(m, 32));
        float mn = fmaxf(mrow1, m);
        float scl = __expf(mrow1 - mn);
        mrow1 = mn;

        float ps = 0.f;
        #pragma unroll
        for (int ct = 0; ct < 4; ++ct)
            #pragma unroll
            for (int r = 0; r < 4; ++r) {
                float p = __expf(s[ct][r] - mn);
                s[ct][r] = p;
                ps += p;
            }
        ps += __shfl_xor(ps, 16);
        ps += __shfl_xor(ps, 32);
        lsum1 = lsum1 * scl + ps;

        // pack P into bf16 pairs (registers only)
        uint pux[4], puy[4];
        #pragma unroll
        for (int ct = 0; ct < 4; ++ct) {
            pux[ct] = pk2(s[ct][0], s[ct][1]);
            puy[ct] = pk2(s[ct][2], s[ct][3]);
        }
        #pragma unroll
        for (int dt = 0; dt < 4; ++dt)
            #pragma unroll
            for (int r = 0; r < 4; ++r) oacc[dt][r] *= scl;

        // O^T += V^T @ P^T, P fragment gathered via shuffles (no LDS round-trip)
        #pragma unroll
        for (int c = 0; c < 2; ++c) {
            int cl = 2 * c, ch = 2 * c + 1;
            uint xA_l = (uint)__shfl((int)pux[cl], srcA);
            uint xA_h = (uint)__shfl((int)pux[ch], srcA);
            uint yA_l = (uint)__shfl((int)puy[cl], srcA);
            uint yA_h = (uint)__shfl((int)puy[ch], srcA);
            uint xB_l = (uint)__shfl((int)pux[cl], srcB);
            uint xB_h = (uint)__shfl((int)pux[ch], srcB);
            uint yB_l = (uint)__shfl((int)puy[cl], srcB);
            uint yB_h = (uint)__shfl((int)puy[ch], srcB);
            uint uu[4];
            uu[0] = hi ? xA_h : xA_l;
            uu[1] = hi ? yA_h : yA_l;
            uu[2] = hi ? xB_h : xB_l;
            uu[3] = hi ? yB_h : yB_l;
            short8v ptf = *(const short8v*)uu;
            __builtin_amdgcn_s_setprio(1);
            #pragma unroll
            for (int dt = 0; dt < 4; ++dt) {
                short8v bv = *(const short8v*)&Vs[dt * 16 + ll][c * 32 + lg * 8];
                oacc[dt] = __builtin_amdgcn_mfma_f32_16x16x32_bf16(bv, ptf, oacc[dt], 0, 0, 0);
            }
            __builtin_amdgcn_s_setprio(0);
        }

        // fold-late: pack next tile's bias (loads had the whole compute to land)
        {
            float amf0 = b2f_lo(am2n), amf1 = b2f_hi(am2n);
            #pragma unroll
            for (int p = 0; p < 8; ++p) {
                int i_s = q0 + trow + 8 * p;
                float v0 = (j_e     < NUM_MEM_) ? 0.f : bvn[p].x + amf0;
                float v1 = (j_e + 1 < NUM_MEM_) ? 0.f : bvn[p].y + amf1;
                v0 = (j_e     <= i_s + NUM_MEM_) ? v0 : -1e30f;
                v1 = (j_e + 1 <= i_s + NUM_MEM_) ? v1 : -1e30f;
                bbc[p] = pk2(v0, v1);
            }
        }
    }

    if (nc == 1) {
        // single-chunk strip: normalize and write attn_ob directly (skip partials)
        float inv = 1.f / lsum1;
        ushort* dst = attn_ob + ((size_t)(b * N_ + i_row)) * QCOLS_ + h * DH_;
        #pragma unroll
        for (int dt = 0; dt < 4; ++dt) {
            uint2 pu;
            pu.x = pk2(oacc[dt][0] * inv, oacc[dt][1] * inv);
            pu.y = pk2(oacc[dt][2] * inv, oacc[dt][3] * inv);
            *(uint2*)(dst + dt * 16 + lg * 4) = pu;
        }
    } else {
        // epilogue: write bf16 partials (O un-normalized) + f32 (m, l)
        int bh_s = b * 8 + h;
        int slot = (bh_s * 32 + qt) * 4 + ci;
        ushort* po = part_O + (size_t)slot * 4096;
        #pragma unroll
        for (int dt = 0; dt < 4; ++dt) {
            uint2 pu;
            pu.x = pk2(oacc[dt][0], oacc[dt][1]);
            pu.y = pk2(oacc[dt][2], oacc[dt][3]);
            *(uint2*)&po[(w * 16 + ll) * 64 + dt * 16 + lg * 4] = pu;
        }
        if (lg == 0) {
            part_ml[(size_t)slot * 128 + (w * 16 + ll) * 2]     = mrow1;
            part_ml[(size_t)slot * 128 + (w * 16 + ll) * 2 + 1] = lsum1;
        }
    }
}

// ---------------- merge bf16 partials -> bf16 attn_o (multi-chunk strips only) ----------------
__global__ __launch_bounds__(256) void merge_kernel(const ushort* __restrict__ part_O,
                                                    const float* __restrict__ part_ml,
                                                    ushort* __restrict__ attn_ob) {
    int bid = blockIdx.x;          // bh*32 + qt
    int qt = bid & 31;
    int nc = (qt + 10) / 9;
    if (nc < 2) return;            // handled by fattn direct-write
    int bh = bid >> 5;
    int b = bh >> 3, h = bh & 7;
    int tid = threadIdx.x;
    int row = tid >> 2;
    int dseg = (tid & 3) * 16;
    int slot0 = bid * 4;

    float M = -1e30f;
    #pragma unroll
    for (int c = 0; c < 4; ++c) {
        if (c >= nc) break;
        M = fmaxf(M, part_ml[(size_t)(slot0 + c) * 128 + row * 2]);
    }
    float den = 0.f;
    float num[16] = {};
    #pragma unroll
    for (int c = 0; c < 4; ++c) {
        if (c >= nc) break;
        float m_c = part_ml[(size_t)(slot0 + c) * 128 + row * 2];
        float l_c = part_ml[(size_t)(slot0 + c) * 128 + row * 2 + 1];
        float wgt = __expf(m_c - M);
        den += wgt * l_c;
        const uint4* src = (const uint4*)(part_O + (size_t)(slot0 + c) * 4096 + row * 64 + dseg);
        uint4 v0 = src[0];
        uint4 v1 = src[1];
        uint uu[8] = { v0.x, v0.y, v0.z, v0.w, v1.x, v1.y, v1.z, v1.w };
        #pragma unroll
        for (int e = 0; e < 8; ++e) {
            num[e * 2 + 0] += wgt * b2f_lo(uu[e]);
            num[e * 2 + 1] += wgt * b2f_hi(uu[e]);
        }
    }
    float inv = 1.f / den;
    ushort o[16];
    #pragma unroll
    for (int e = 0; e < 16; ++e) o[e] = f2b(num[e] * inv);
    int i = qt * 64 + row;
    ushort* dst = attn_ob + ((size_t)(b * N_ + i)) * QCOLS_ + h * DH_ + dseg;
    *(int4*)dst = *(int4*)o;
    *(int4*)(dst + 8) = *(int4*)(o + 8);
}

extern "C" void kernel_launch(void* const* d_in, const int* in_sizes, int n_in,
                              void* d_out, int out_size, void* d_ws, size_t ws_size,
                              hipStream_t stream) {
    const float* x         = (const float*)d_in[0];
    const float* attn_bias = (const float*)d_in[1];
    const float* gamma     = (const float*)d_in[2];
    const float* Wq        = (const float*)d_in[3];
    const float* Wkv       = (const float*)d_in[4];
    const float* mem_kv    = (const float*)d_in[5];
    const float* Wout      = (const float*)d_in[6];
    const int*   mask      = (const int*)d_in[7];
    float* out = (float*)d_out;

    char* wsb = (char*)d_ws;
    ushort* xb      = (ushort*)wsb;                    // 8 MB
    ushort* xnb     = (ushort*)(wsb + (8u  << 20));    // 8 MB
    ushort* qb      = (ushort*)(wsb + (16u << 20));    // 4 MB
    ushort* attn_ob = (ushort*)(wsb + (20u << 20));    // 4 MB
    ushort* Kb      = (ushort*)(wsb + (24u << 20));    // 0.56 MB
    ushort* Vt      = (ushort*)(wsb + (25u << 20));    // 0.56 MB
    ushort* Wqt     = (ushort*)(wsb + (26u << 20));    // 1 MB
    ushort* Wkvt    = (ushort*)(wsb + (27u << 20));    // 0.25 MB
    ushort* Woutt   = (ushort*)(wsb + (28u << 20));    // 1 MB
    ushort* amask   = (ushort*)(wsb + (29u << 20));    // 8.5 KB
    ushort* part_O  = (ushort*)(wsb + (32u << 20));    // 16 MB (2048 slots x 8KB)
    float*  part_ml = (float*)(wsb + (64u << 20));     // 1 MB

    ln_prep_kernel<<<ROWS_ + 657, 256, 0, stream>>>(x, gamma, Wq, Wkv, Wout, mem_kv, mask,
                                                    xb, xnb, Wqt, Wkvt, Woutt, Kb, Vt, amask);
    gemm01_kernel<<<640, 256, 0, stream>>>(xnb, Wqt, qb, xb, Wkvt, Kb, Vt);
    fattn_split_kernel<<<16 * CHUNKS_PER_BH_, 256, 0, stream>>>(qb, Kb, Vt, attn_bias, amask,
                                                                part_O, part_ml, attn_ob);
    merge_kernel<<<512, 256, 0, stream>>>(part_O, part_ml, attn_ob);
    gemm_out_kernel<<<dim3(DIM_ / 64, ROWS_ / 128), 256, 0, stream>>>(attn_ob, Woutt, out, ROWS_, DIM_, QCOLS_);
}